// Round 3
// baseline (4034.621 us; speedup 1.0000x reference)
//
#include <hip/hip_runtime.h>
#include <cstdint>
#include <cstddef>

// ---------------- constants ----------------
constexpr int CB = 32;      // batch
constexpr int CS = 32;      // question seq
constexpr int CFL = 640;    // F*L
constexpr int CT = 24;      // steps

typedef __attribute__((ext_vector_type(8))) short short8;
typedef __attribute__((ext_vector_type(4))) float floatx4;

// ---------------- helpers ----------------
__device__ __forceinline__ float bf2f(short s) {
  return __uint_as_float(((unsigned int)(unsigned short)s) << 16);
}
__device__ __forceinline__ short f2bf(float f) {
  unsigned int u = __float_as_uint(f);
  u = (u + 0x7FFFu + ((u >> 16) & 1u)) >> 16;
  return (short)u;
}
// exact split: f = hi + lo + O(2^-18 |f|)
__device__ __forceinline__ void split8(const float* __restrict__ p, short8& hi, short8& lo) {
#pragma unroll
  for (int j = 0; j < 8; ++j) {
    float f = p[j];
    short h = f2bf(f);
    hi[j] = h;
    lo[j] = f2bf(f - bf2f(h));
  }
}
__device__ __forceinline__ float sigf(float x) { return 1.f / (1.f + __expf(-x)); }
__device__ __forceinline__ float ftanh(float x) {
  float e = __expf(2.f * x);
  return 1.f - 2.f / (e + 1.f);
}

// ---------------- ws layout (bytes), total 71,516,160 B = 68.2 MiB ----------------
constexpr size_t OFF_FPROJ = 0;            // [20480][512] f32 = 41,943,040
constexpr size_t OFF_QPROJ = 41943040;     // [1024][512]  f32 =  2,097,152  (region A ends 44,040,192)
constexpr size_t OFF_BTA   = 44040192;     // [3072][512]  f32 =  6,291,456
constexpr size_t OFF_BTC   = 50331648;     // [2048][1536] f32 = 12,582,912
constexpr size_t OFF_ACT   = 62914560;     // [768][2560]  f32 =  7,864,320  (setup-alias: BTW1 [512][512] f32)
constexpr size_t OFF_HA    = 70778880;     // [32][3072]   f32 =    393,216
constexpr size_t OFF_H     = 71172096;     // [32][512]    f32 =     65,536
constexpr size_t OFF_XQ    = 71237632;     // [32][1024]   f32 =    131,072
constexpr size_t OFF_C     = 71368704;     // [32][512]    f32 =     65,536
constexpr size_t OFF_FS    = 71434240;     // [32][640]    f32 =     81,920 -> 71,516,160
// phase-2 (after recurrence; FPROJ/QPROJ/BTC dead):
constexpr size_t OFF_BTY   = 0;            // [32000][512] bf16 = 32,768,000
constexpr size_t OFF_BTR   = 32768000;     // [1024][2560] f32  = 10,485,760 (ends 43,253,760 < 44,040,192)
constexpr size_t OFF_RBUF  = OFF_BTC;      // [768][1024]  f32  =  3,145,728
constexpr size_t OFF_MBUF  = OFF_BTC + 3145728;  // [768][512] bf16 = 786,432

// ---------------- init: zero h and c ----------------
__global__ void init_kernel(float* h, float* c_buf) {
  int i = blockIdx.x * 256 + threadIdx.x;
  if (i < 16384) { h[i] = 0.f; c_buf[i] = 0.f; }
}

// ---------------- gather prev tokens into act_all cols [512,1024) ----------------
__global__ void gather_prev_kernel(const int* __restrict__ target, const float* __restrict__ emb,
                                   float* __restrict__ act_all) {
  int r = blockIdx.x;            // 0..767 = t*32+b
  int t = r >> 5, b = r & 31;
  int tok = (t == 0) ? -1 : target[b * CT + (t - 1)];
  for (int e = threadIdx.x; e < 512; e += 256) {
    float v = (tok < 0) ? 0.f : emb[(size_t)tok * 512 + e];
    act_all[(size_t)r * 2560 + 512 + e] = v;
  }
}

// ---------------- fp32 tiled transpose: dst[dst_row0+n][dst_col0+k] = src[src_row0+k][n] ----------------
__global__ __launch_bounds__(256) void transpose_f32_kernel(
    const float* __restrict__ src, int src_ld, int src_row0,
    float* __restrict__ dst, int dst_ld, int dst_row0, int dst_col0) {
  __shared__ float tile[64][65];
  int n0 = blockIdx.x * 64, k0 = blockIdx.y * 64;
  for (int it = 0; it < 16; ++it) {
    int idx = threadIdx.x + it * 256;
    int kk = idx >> 6, nn = idx & 63;
    tile[kk][nn] = src[(size_t)(src_row0 + k0 + kk) * src_ld + n0 + nn];
  }
  __syncthreads();
  for (int it = 0; it < 16; ++it) {
    int idx = threadIdx.x + it * 256;
    int nn = idx >> 6, kk = idx & 63;
    dst[(size_t)(dst_row0 + n0 + nn) * dst_ld + dst_col0 + k0 + kk] = tile[kk][nn];
  }
}

// ---------------- fp32 -> bf16 transpose (for Wy) ----------------
__global__ __launch_bounds__(256) void transpose_f2b_kernel(
    const float* __restrict__ src, int src_ld,
    short* __restrict__ dst, int dst_ld) {
  __shared__ float tile[64][65];
  int n0 = blockIdx.x * 64, k0 = blockIdx.y * 64;
  for (int it = 0; it < 16; ++it) {
    int idx = threadIdx.x + it * 256;
    int kk = idx >> 6, nn = idx & 63;
    tile[kk][nn] = src[(size_t)(k0 + kk) * src_ld + n0 + nn];
  }
  __syncthreads();
  for (int it = 0; it < 16; ++it) {
    int idx = threadIdx.x + it * 256;
    int nn = idx >> 6, kk = idx & 63;
    dst[(size_t)(n0 + nn) * dst_ld + k0 + kk] = f2bf(tile[kk][nn]);
  }
}

// ---------------- 3-term split GEMM: C[M,N] f32 = A[M,K]f32 @ BT[N,K]f32^T ----------------
// grid.x = M/64, grid.y = N/128, 256 threads.
__global__ __launch_bounds__(256) void gemm3_bt_kernel(
    const float* __restrict__ A, const float* __restrict__ BT,
    float* __restrict__ C, int N, int K) {
  const int lane = threadIdx.x & 63;
  const int wave = threadIdx.x >> 6;
  const int quad = lane >> 4;
  const int l16 = lane & 15;
  const int m_base = blockIdx.x * 64 + (wave & 1) * 32;
  const int n_base = blockIdx.y * 128 + (wave >> 1) * 64;

  floatx4 acc[2][4];
#pragma unroll
  for (int mi = 0; mi < 2; ++mi)
#pragma unroll
    for (int ni = 0; ni < 4; ++ni) acc[mi][ni] = (floatx4){0.f, 0.f, 0.f, 0.f};

  const float* a0p = A + (size_t)(m_base + l16) * K + quad * 8;
  const float* a1p = a0p + (size_t)16 * K;
  const float* b0p = BT + (size_t)(n_base + l16) * K + quad * 8;

  for (int k0 = 0; k0 < K; k0 += 32) {
    short8 a0h, a0l, a1h, a1l;
    split8(a0p + k0, a0h, a0l);
    split8(a1p + k0, a1h, a1l);
#pragma unroll
    for (int ni = 0; ni < 4; ++ni) {
      short8 bh, bl;
      split8(b0p + (size_t)(ni * 16) * K + k0, bh, bl);
      acc[0][ni] = __builtin_amdgcn_mfma_f32_16x16x32_bf16(a0h, bh, acc[0][ni], 0, 0, 0);
      acc[0][ni] = __builtin_amdgcn_mfma_f32_16x16x32_bf16(a0l, bh, acc[0][ni], 0, 0, 0);
      acc[0][ni] = __builtin_amdgcn_mfma_f32_16x16x32_bf16(a0h, bl, acc[0][ni], 0, 0, 0);
      acc[1][ni] = __builtin_amdgcn_mfma_f32_16x16x32_bf16(a1h, bh, acc[1][ni], 0, 0, 0);
      acc[1][ni] = __builtin_amdgcn_mfma_f32_16x16x32_bf16(a1l, bh, acc[1][ni], 0, 0, 0);
      acc[1][ni] = __builtin_amdgcn_mfma_f32_16x16x32_bf16(a1h, bl, acc[1][ni], 0, 0, 0);
    }
  }
#pragma unroll
  for (int mi = 0; mi < 2; ++mi)
#pragma unroll
    for (int ni = 0; ni < 4; ++ni) {
      int col = n_base + ni * 16 + l16;
#pragma unroll
      for (int r = 0; r < 4; ++r) {
        int row = m_base + mi * 16 + quad * 4 + r;
        C[(size_t)row * N + col] = acc[mi][ni][r];
      }
    }
}

// ---------------- M=32 3-term GEMM: grid.x = N/128 ----------------
__global__ __launch_bounds__(256) void gemm3_bt_m32_kernel(
    const float* __restrict__ A, const float* __restrict__ BT,
    float* __restrict__ C, int N, int K) {
  const int lane = threadIdx.x & 63;
  const int wave = threadIdx.x >> 6;
  const int quad = lane >> 4;
  const int l16 = lane & 15;
  const int n_base = blockIdx.x * 128 + wave * 32;

  floatx4 acc[2][2];
#pragma unroll
  for (int mi = 0; mi < 2; ++mi)
#pragma unroll
    for (int ni = 0; ni < 2; ++ni) acc[mi][ni] = (floatx4){0.f, 0.f, 0.f, 0.f};

  const float* a0p = A + (size_t)l16 * K + quad * 8;
  const float* a1p = a0p + (size_t)16 * K;
  const float* b0p = BT + (size_t)(n_base + l16) * K + quad * 8;

  for (int k0 = 0; k0 < K; k0 += 32) {
    short8 a0h, a0l, a1h, a1l;
    split8(a0p + k0, a0h, a0l);
    split8(a1p + k0, a1h, a1l);
#pragma unroll
    for (int ni = 0; ni < 2; ++ni) {
      short8 bh, bl;
      split8(b0p + (size_t)(ni * 16) * K + k0, bh, bl);
      acc[0][ni] = __builtin_amdgcn_mfma_f32_16x16x32_bf16(a0h, bh, acc[0][ni], 0, 0, 0);
      acc[0][ni] = __builtin_amdgcn_mfma_f32_16x16x32_bf16(a0l, bh, acc[0][ni], 0, 0, 0);
      acc[0][ni] = __builtin_amdgcn_mfma_f32_16x16x32_bf16(a0h, bl, acc[0][ni], 0, 0, 0);
      acc[1][ni] = __builtin_amdgcn_mfma_f32_16x16x32_bf16(a1h, bh, acc[1][ni], 0, 0, 0);
      acc[1][ni] = __builtin_amdgcn_mfma_f32_16x16x32_bf16(a1l, bh, acc[1][ni], 0, 0, 0);
      acc[1][ni] = __builtin_amdgcn_mfma_f32_16x16x32_bf16(a1h, bl, acc[1][ni], 0, 0, 0);
    }
  }
#pragma unroll
  for (int mi = 0; mi < 2; ++mi)
#pragma unroll
    for (int ni = 0; ni < 2; ++ni) {
      int col = n_base + ni * 16 + l16;
#pragma unroll
      for (int r = 0; r < 4; ++r) {
        int row = mi * 16 + quad * 4 + r;
        C[(size_t)row * N + col] = acc[mi][ni][r];
      }
    }
}

// ---------------- fact scores: fs[b,i] = sum_a tanh(fproj + hf) * vf ----------------
__global__ __launch_bounds__(256) void f_scores_kernel(
    const float* __restrict__ f_proj, const float* __restrict__ hA,
    const float* __restrict__ vf, float* __restrict__ fs_buf) {
  const int b = blockIdx.x & 31;
  const int chunk = blockIdx.x >> 5;
  const int lane = threadIdx.x & 63;
  const int wave = threadIdx.x >> 6;

  float hf8[8], vf8[8];
  const float* hp = hA + b * 3072 + 512 + lane * 8;
#pragma unroll
  for (int j = 0; j < 8; ++j) hf8[j] = hp[j];
  const float* vp = vf + lane * 8;
#pragma unroll
  for (int j = 0; j < 8; ++j) vf8[j] = vp[j];

  for (int ii = 0; ii < 16; ++ii) {
    int i = chunk * 64 + wave * 16 + ii;
    const float* fp = f_proj + (size_t)(b * CFL + i) * 512 + lane * 8;
    float s = 0.f;
#pragma unroll
    for (int j = 0; j < 8; ++j) s += ftanh(fp[j] + hf8[j]) * vf8[j];
    for (int off = 32; off; off >>= 1) s += __shfl_xor(s, off);
    if (lane == 0) fs_buf[b * CFL + i] = s;
  }
}

// ---------------- per-batch: top-64 select + f-softmax + fvec + q-attn + qvec ----------------
__global__ __launch_bounds__(256) void attn_select_kernel(
    const float* __restrict__ fs_buf, const float* __restrict__ q_proj,
    const float* __restrict__ hA, const float* __restrict__ facts,
    const float* __restrict__ bq, const float* __restrict__ vq,
    float* __restrict__ xq, float* __restrict__ act_all, int step) {
  const int b = blockIdx.x;
  const int tid = threadIdx.x;
  const int lane = tid & 63;
  const int wave = tid >> 6;

  __shared__ float fs_l[640];
  __shared__ unsigned int keys[640];
  __shared__ float red_f[4];
  __shared__ unsigned int red_u[4];
  __shared__ int list_idx[64];
  __shared__ float list_w[64];
  __shared__ float qs_l[32];
  __shared__ float qw_l[32];

  if (tid < 64) list_idx[tid] = tid;   // defensive prefill

  float lmax = -3.0e38f;
  for (int i = tid; i < 640; i += 256) {
    float v = fs_buf[b * CFL + i];
    fs_l[i] = v;
    unsigned int u = __float_as_uint(v);
    keys[i] = (u & 0x80000000u) ? ~u : (u | 0x80000000u);
    lmax = fmaxf(lmax, v);
  }
  for (int off = 32; off; off >>= 1) lmax = fmaxf(lmax, __shfl_xor(lmax, off));
  if (lane == 0) red_f[wave] = lmax;
  __syncthreads();
  float maxv = fmaxf(fmaxf(red_f[0], red_f[1]), fmaxf(red_f[2], red_f[3]));
  __syncthreads();

  // binary search for tau = 64th-largest key
  unsigned int lo = 0u, hi = 0xFFFFFFFFu;
  for (int iter = 0; iter < 32; ++iter) {
    unsigned int span = hi - lo;
    unsigned int mid = lo + (span >> 1) + (span & 1u);
    int cnt = 0;
    for (int i = tid; i < 640; i += 256) cnt += (keys[i] >= mid) ? 1 : 0;
    for (int off = 32; off; off >>= 1) cnt += __shfl_xor(cnt, off);
    if (lane == 0) red_u[wave] = (unsigned int)cnt;
    __syncthreads();
    unsigned int total = red_u[0] + red_u[1] + red_u[2] + red_u[3];
    if (total >= 64u) lo = mid; else hi = mid - 1u;
    __syncthreads();
  }
  unsigned int tau = lo;

  {
    int cg = 0;
    for (int i = tid; i < 640; i += 256) cg += (keys[i] > tau) ? 1 : 0;
    for (int off = 32; off; off >>= 1) cg += __shfl_xor(cg, off);
    if (lane == 0) red_u[wave] = (unsigned int)cg;
    __syncthreads();
  }
  int cnt_gt = (int)(red_u[0] + red_u[1] + red_u[2] + red_u[3]);
  int ties_take = 64 - cnt_gt;
  if (ties_take < 0) ties_take = 0;
  __syncthreads();

  // compact: strict-greater first (ascending i), then ==tau (ascending i)
  if (wave == 0) {
    int ngt = 0, neq = 0;
    for (int c = 0; c < 10; ++c) {
      int i = c * 64 + lane;
      unsigned int k = keys[i];
      unsigned long long mgt = __ballot(k > tau);
      unsigned long long meq = __ballot(k == tau);
      unsigned long long below = (1ull << lane) - 1ull;
      if (k > tau) {
        int pos = ngt + __popcll(mgt & below);
        if (pos < 64) list_idx[pos] = i;
      } else if (k == tau) {
        int er = neq + __popcll(meq & below);
        int pos = cnt_gt + er;
        if (er < ties_take && pos < 64) list_idx[pos] = i;
      }
      ngt += __popcll(mgt);
      neq += __popcll(meq);
    }
  }
  __syncthreads();

  if (wave == 0) {
    float v = fs_l[list_idx[lane]];
    float e = __expf(v - maxv);
    float s = e;
    for (int off = 32; off; off >>= 1) s += __shfl_xor(s, off);
    list_w[lane] = e / s;
  }
  __syncthreads();

  // fvec: weighted sum over selected 64 rows (fp32)
  const int d0 = tid, d1 = tid + 256;
  float f0 = 0.f, f1 = 0.f;
  for (int j = 0; j < 64; ++j) {
    int idx = list_idx[j];
    float w = list_w[j];
    const float* fr = facts + (size_t)(b * CFL + idx) * 512;
    f0 += w * fr[d0];
    f1 += w * fr[d1];
  }
  const int row = step * CB + b;
  xq[b * 1024 + d0] = f0;
  xq[b * 1024 + d1] = f1;
  act_all[(size_t)row * 2560 + 1024 + d0] = f0;
  act_all[(size_t)row * 2560 + 1024 + d1] = f1;

  // q scores
  {
    float hq8[8], vq8[8];
    const float* hp = hA + b * 3072 + lane * 8;
#pragma unroll
    for (int j = 0; j < 8; ++j) hq8[j] = hp[j];
    const float* vp = vq + lane * 8;
#pragma unroll
    for (int j = 0; j < 8; ++j) vq8[j] = vp[j];
    for (int ss = 0; ss < 8; ++ss) {
      int s = wave * 8 + ss;
      const float* qp = q_proj + (size_t)(b * CS + s) * 512 + lane * 8;
      float acc = 0.f;
#pragma unroll
      for (int j = 0; j < 8; ++j) acc += ftanh(qp[j] + hq8[j]) * vq8[j];
      for (int off = 32; off; off >>= 1) acc += __shfl_xor(acc, off);
      if (lane == 0) qs_l[s] = acc;
    }
  }
  __syncthreads();
  if (wave == 0 && lane < 32) {
    float v = qs_l[lane];
    float m = v;
    for (int off = 16; off; off >>= 1) m = fmaxf(m, __shfl_xor(m, off));
    float e = __expf(v - m);
    float s = e;
    for (int off = 16; off; off >>= 1) s += __shfl_xor(s, off);
    qw_l[lane] = e / s;
  }
  __syncthreads();

  // qvec
  float q0 = 0.f, q1 = 0.f;
  for (int s = 0; s < 32; ++s) {
    float w = qw_l[s];
    const float* er = bq + (size_t)(b * CS + s) * 512;
    q0 += w * er[d0];
    q1 += w * er[d1];
  }
  xq[b * 1024 + 512 + d0] = q0;
  xq[b * 1024 + 512 + d1] = q1;
  act_all[(size_t)row * 2560 + 1536 + d0] = q0;
  act_all[(size_t)row * 2560 + 1536 + d1] = q1;
  act_all[(size_t)row * 2560 + 2048 + d0] = q0;
  act_all[(size_t)row * 2560 + 2048 + d1] = q1;
}

// ---------------- LSTM step: gates GEMM (fvec,qvec,prev; 3-term) + cell update ----------------
// grid = 16 (unit slabs of 32), 4 waves = 4 gates (i,f,g,o)
__global__ __launch_bounds__(256) void lstm_step_kernel(
    const float* __restrict__ xq, const float* __restrict__ BTC,
    const float* __restrict__ hA, const float* __restrict__ act_all,
    const float* __restrict__ bias, float* __restrict__ c_buf,
    float* __restrict__ h, float* __restrict__ act_out, int step) {
  const int lane = threadIdx.x & 63;
  const int wave = threadIdx.x >> 6;
  const int quad = lane >> 4;
  const int l16 = lane & 15;
  const int u0 = blockIdx.x * 32;
  const int gbase = wave * 512 + u0;

  floatx4 acc[2][2];
#pragma unroll
  for (int mi = 0; mi < 2; ++mi)
#pragma unroll
    for (int ni = 0; ni < 2; ++ni) acc[mi][ni] = (floatx4){0.f, 0.f, 0.f, 0.f};

  const float* b0p = BTC + (size_t)(gbase + l16) * 1536 + quad * 8;

  // part 1: fvec+qvec from xq [32][1024], BTC cols [0,1024)
  {
    const float* a0p = xq + (size_t)l16 * 1024 + quad * 8;
    const float* a1p = a0p + (size_t)16 * 1024;
    for (int k0 = 0; k0 < 1024; k0 += 32) {
      short8 a0h, a0l, a1h, a1l;
      split8(a0p + k0, a0h, a0l);
      split8(a1p + k0, a1h, a1l);
#pragma unroll
      for (int ni = 0; ni < 2; ++ni) {
        short8 bh, bl;
        split8(b0p + (size_t)(ni * 16) * 1536 + k0, bh, bl);
        acc[0][ni] = __builtin_amdgcn_mfma_f32_16x16x32_bf16(a0h, bh, acc[0][ni], 0, 0, 0);
        acc[0][ni] = __builtin_amdgcn_mfma_f32_16x16x32_bf16(a0l, bh, acc[0][ni], 0, 0, 0);
        acc[0][ni] = __builtin_amdgcn_mfma_f32_16x16x32_bf16(a0h, bl, acc[0][ni], 0, 0, 0);
        acc[1][ni] = __builtin_amdgcn_mfma_f32_16x16x32_bf16(a1h, bh, acc[1][ni], 0, 0, 0);
        acc[1][ni] = __builtin_amdgcn_mfma_f32_16x16x32_bf16(a1l, bh, acc[1][ni], 0, 0, 0);
        acc[1][ni] = __builtin_amdgcn_mfma_f32_16x16x32_bf16(a1h, bl, acc[1][ni], 0, 0, 0);
      }
    }
  }
  // part 2: prev from act_all[(step*32+m)][512+k], BTC cols [1024,1536)
  {
    const float* a0p = act_all + (size_t)(step * CB + l16) * 2560 + 512 + quad * 8;
    const float* a1p = a0p + (size_t)16 * 2560;
    for (int k0 = 0; k0 < 512; k0 += 32) {
      short8 a0h, a0l, a1h, a1l;
      split8(a0p + k0, a0h, a0l);
      split8(a1p + k0, a1h, a1l);
#pragma unroll
      for (int ni = 0; ni < 2; ++ni) {
        short8 bh, bl;
        split8(b0p + (size_t)(ni * 16) * 1536 + 1024 + k0, bh, bl);
        acc[0][ni] = __builtin_amdgcn_mfma_f32_16x16x32_bf16(a0h, bh, acc[0][ni], 0, 0, 0);
        acc[0][ni] = __builtin_amdgcn_mfma_f32_16x16x32_bf16(a0l, bh, acc[0][ni], 0, 0, 0);
        acc[0][ni] = __builtin_amdgcn_mfma_f32_16x16x32_bf16(a0h, bl, acc[0][ni], 0, 0, 0);
        acc[1][ni] = __builtin_amdgcn_mfma_f32_16x16x32_bf16(a1h, bh, acc[1][ni], 0, 0, 0);
        acc[1][ni] = __builtin_amdgcn_mfma_f32_16x16x32_bf16(a1l, bh, acc[1][ni], 0, 0, 0);
        acc[1][ni] = __builtin_amdgcn_mfma_f32_16x16x32_bf16(a1h, bl, acc[1][ni], 0, 0, 0);
      }
    }
  }

  __shared__ float zbuf[4][32][32];
#pragma unroll
  for (int mi = 0; mi < 2; ++mi)
#pragma unroll
    for (int ni = 0; ni < 2; ++ni) {
      int ul = ni * 16 + l16;
      int n = gbase + ul;
#pragma unroll
      for (int r = 0; r < 4; ++r) {
        int bb = mi * 16 + quad * 4 + r;
        zbuf[wave][bb][ul] = acc[mi][ni][r] + hA[bb * 3072 + 1024 + n] + bias[n];
      }
    }
  __syncthreads();

  for (int e = threadIdx.x; e < 1024; e += 256) {
    int bb = e >> 5, u = e & 31;
    float zi = zbuf[0][bb][u], zf = zbuf[1][bb][u], zg = zbuf[2][bb][u], zo = zbuf[3][bb][u];
    int ci = bb * 512 + u0 + u;
    float cold = c_buf[ci];
    float c2 = sigf(zf) * cold + sigf(zi) * ftanh(zg);
    float h2 = sigf(zo) * ftanh(c2);
    c_buf[ci] = c2;
    h[ci] = h2;
    act_out[(size_t)(step * CB + bb) * 2560 + (u0 + u)] = h2;
  }
}

// ---------------- maxout (+ biases) ----------------
__global__ void maxout_kernel(const float* __restrict__ R, const float* __restrict__ br,
                              const float* __restrict__ bur, const float* __restrict__ bvr,
                              short* __restrict__ m_buf) {
  int idx = blockIdx.x * 256 + threadIdx.x;  // < 768*512
  int r = idx >> 9, j = idx & 511;
  int n0 = j * 2, n1 = j * 2 + 1;
  float v0 = R[(size_t)r * 1024 + n0] + br[n0] + bur[n0] + bvr[n0];
  float v1 = R[(size_t)r * 1024 + n1] + br[n1] + bur[n1] + bvr[n1];
  m_buf[(size_t)r * 512 + j] = f2bf(fmaxf(v0, v1));
}

// ---------------- logits GEMM: bf16 A,B -> f32 out + f32 bias ----------------
__global__ __launch_bounds__(256) void gemm_bf_kernel(
    const short* __restrict__ A, const short* __restrict__ BT,
    float* __restrict__ C, const float* __restrict__ bias, int N, int K) {
  const int lane = threadIdx.x & 63;
  const int wave = threadIdx.x >> 6;
  const int quad = lane >> 4;
  const int l16 = lane & 15;
  const int m_base = blockIdx.x * 64 + (wave & 1) * 32;
  const int n_base = blockIdx.y * 128 + (wave >> 1) * 64;

  floatx4 acc[2][4];
#pragma unroll
  for (int mi = 0; mi < 2; ++mi)
#pragma unroll
    for (int ni = 0; ni < 4; ++ni) acc[mi][ni] = (floatx4){0.f, 0.f, 0.f, 0.f};

  const short* a0p = A + (size_t)(m_base + l16) * K + quad * 8;
  const short* a1p = a0p + (size_t)16 * K;
  const short* b0p = BT + (size_t)(n_base + l16) * K + quad * 8;

  for (int k0 = 0; k0 < K; k0 += 32) {
    short8 a0 = *(const short8*)(a0p + k0);
    short8 a1 = *(const short8*)(a1p + k0);
#pragma unroll
    for (int ni = 0; ni < 4; ++ni) {
      short8 bb = *(const short8*)(b0p + (size_t)(ni * 16) * K + k0);
      acc[0][ni] = __builtin_amdgcn_mfma_f32_16x16x32_bf16(a0, bb, acc[0][ni], 0, 0, 0);
      acc[1][ni] = __builtin_amdgcn_mfma_f32_16x16x32_bf16(a1, bb, acc[1][ni], 0, 0, 0);
    }
  }
#pragma unroll
  for (int mi = 0; mi < 2; ++mi)
#pragma unroll
    for (int ni = 0; ni < 4; ++ni) {
      int col = n_base + ni * 16 + l16;
#pragma unroll
      for (int r = 0; r < 4; ++r) {
        int row = m_base + mi * 16 + quad * 4 + r;
        C[(size_t)row * N + col] = acc[mi][ni][r] + bias[col];
      }
    }
}

// ---------------- launch ----------------
extern "C" void kernel_launch(void* const* d_in, const int* in_sizes, int n_in,
                              void* d_out, int out_size, void* d_ws, size_t ws_size,
                              hipStream_t stream) {
  const float* bq     = (const float*)d_in[0];
  const float* facts  = (const float*)d_in[1];
  const int*   target = (const int*)d_in[2];
  const float* emb    = (const float*)d_in[4];
  const float* lstm_k = (const float*)d_in[5];
  const float* lstm_r = (const float*)d_in[6];
  const float* lstm_b = (const float*)d_in[7];
  const float* Wq1 = (const float*)d_in[8];
  const float* Wq2 = (const float*)d_in[9];
  const float* vq  = (const float*)d_in[10];
  const float* Wf1 = (const float*)d_in[11];
  const float* Wf2 = (const float*)d_in[12];
  const float* vf  = (const float*)d_in[13];
  const float* Wr  = (const float*)d_in[14];
  const float* br  = (const float*)d_in[15];
  const float* Ur  = (const float*)d_in[16];
  const float* bur = (const float*)d_in[17];
  const float* Vr  = (const float*)d_in[18];
  const float* bvr = (const float*)d_in[19];
  const float* Wy  = (const float*)d_in[20];
  const float* by  = (const float*)d_in[21];

  char* ws = (char*)d_ws;
  float* f_proj  = (float*)(ws + OFF_FPROJ);
  float* q_proj  = (float*)(ws + OFF_QPROJ);
  float* BTA     = (float*)(ws + OFF_BTA);
  float* BTC     = (float*)(ws + OFF_BTC);
  float* act_all = (float*)(ws + OFF_ACT);
  float* BTW1    = (float*)(ws + OFF_ACT);   // setup-phase alias (dies before gather_prev)
  float* hA      = (float*)(ws + OFF_HA);
  float* h_buf   = (float*)(ws + OFF_H);
  float* xq      = (float*)(ws + OFF_XQ);
  float* c_buf   = (float*)(ws + OFF_C);
  float* fs_buf  = (float*)(ws + OFF_FS);
  short* BTY     = (short*)(ws + OFF_BTY);
  float* BTR     = (float*)(ws + OFF_BTR);
  float* R_buf   = (float*)(ws + OFF_RBUF);
  short* m_buf   = (short*)(ws + OFF_MBUF);
  float* out     = (float*)d_out;

  auto T = [&](const float* src, int sld, int srow0, float* dst, int dld,
               int drow0, int dcol0, int NR, int NK) {
    transpose_f32_kernel<<<dim3(NR / 64, NK / 64), 256, 0, stream>>>(src, sld, srow0, dst, dld, drow0, dcol0);
  };

  // --- persistent transposed weights (fp32) ---
  T(Wq2, 512, 0, BTA, 512, 0, 0, 512, 512);
  T(Wf2, 512, 0, BTA, 512, 512, 0, 512, 512);
  T(lstm_r, 2048, 0, BTA, 512, 1024, 0, 2048, 512);
  T(lstm_k, 2048, 512, BTC, 1536, 0, 0, 2048, 512);      // fvec weights
  T(lstm_k, 2048, 1024, BTC, 1536, 0, 512, 2048, 512);   // qvec weights
  T(lstm_k, 2048, 0, BTC, 1536, 0, 1024, 2048, 512);     // prev weights

  // --- hoisted projections (BTW1 aliases act_all; used before gather_prev) ---
  T(Wq1, 512, 0, BTW1, 512, 0, 0, 512, 512);
  gemm3_bt_kernel<<<dim3(16, 4), 256, 0, stream>>>(bq, BTW1, q_proj, 512, 512);
  T(Wf1, 512, 0, BTW1, 512, 0, 0, 512, 512);
  gemm3_bt_kernel<<<dim3(320, 4), 256, 0, stream>>>(facts, BTW1, f_proj, 512, 512);

  // --- init recurrent state + prev tokens (clobbers BTW1 alias — after projections) ---
  init_kernel<<<64, 256, 0, stream>>>(h_buf, c_buf);
  gather_prev_kernel<<<768, 256, 0, stream>>>(target, emb, act_all);

  // --- recurrence ---
  for (int t = 0; t < CT; ++t) {
    gemm3_bt_m32_kernel<<<24, 256, 0, stream>>>(h_buf, BTA, hA, 3072, 512);
    f_scores_kernel<<<320, 256, 0, stream>>>(f_proj, hA, vf, fs_buf);
    attn_select_kernel<<<32, 256, 0, stream>>>(fs_buf, q_proj, hA, facts, bq, vq, xq, act_all, t);
    lstm_step_kernel<<<16, 256, 0, stream>>>(xq, BTC, hA, act_all, lstm_b, c_buf, h_buf, act_all, t);
  }

  // --- end-stage weights into dead regions ---
  T(Wr, 1024, 0, BTR, 2560, 0, 0, 1024, 512);
  T(Ur, 1024, 0, BTR, 2560, 0, 512, 1024, 1536);
  T(Vr, 1024, 0, BTR, 2560, 0, 2048, 1024, 512);
  transpose_f2b_kernel<<<dim3(500, 8), 256, 0, stream>>>(Wy, 32000, BTY, 512);

  // --- batched readout + maxout + logits ---
  gemm3_bt_kernel<<<dim3(12, 8), 256, 0, stream>>>(act_all, BTR, R_buf, 1024, 2560);
  maxout_kernel<<<1536, 256, 0, stream>>>(R_buf, br, bur, bvr, m_buf);
  gemm_bf_kernel<<<dim3(12, 250), 256, 0, stream>>>(m_buf, BTY, out, by, 32000, 512);
}